// Round 18
// baseline (185.080 us; speedup 1.0000x reference)
//
#include <hip/hip_runtime.h>
#include <stdint.h>

// Problem constants: B=4, N=32768, K=16, nqueries=2048, stride=16.
// Two-kernel scheme:
//  1) repack_soa: xyz (AoS) -> ws SoA x[],y[],z[] per batch (1.57 MB).
//  2) knn_soa (R9 geometry: 2 queries/wave, full stream, 4096 waves):
//     packed-FP32 gate via v_pk_fma_f32 with ALL-PACKED operands (the
//     legal form; R8's failure was scalar-broadcast src). SoA layout puts
//     point pairs {p2u,p2u+1} in aligned VGPR pairs straight from
//     dwordx4 loads -> zero packing movs. 13 VALU / 2 points / pair of
//     queries vs 26 scalar. Same fma formula as R9 -> same error bound;
//     conservative margin + EXACT numpy-ordered recompute & insert keep
//     results bit-exact. Fallback to proven R9 AoS kernel if ws small.
#define NPTS  32768
#define NQ    2048
#define KNN   16
#define NB    4
#define BLOCK 256
#define WPB   4               // waves per block; 2 queries per wave
#define PPL   8               // points per lane per iteration
#define ITERS (NPTS / (64 * PPL))   // 64
#define GATE_MARGIN 5e-4f

typedef float f32x2 __attribute__((ext_vector_type(2)));

__device__ __forceinline__ int dpp_shr1_i(int x) {
    // row_shr:1 within 16-lane rows; row-start lane keeps old (bound_ctrl=0)
    return __builtin_amdgcn_update_dpp(x, x, 0x111, 0xf, 0xf, false);
}
__device__ __forceinline__ float dpp_shr1_f(float x) {
    return __int_as_float(dpp_shr1_i(__float_as_int(x)));
}
__device__ __forceinline__ float readlane_f(float x, int l) {
    return __int_as_float(__builtin_amdgcn_readlane(__float_as_int(x), l));
}

// Packed helpers — ALL operands are 64-bit register pairs (legal VOP3P).
__device__ __forceinline__ f32x2 pk_mul(f32x2 a, f32x2 b) {
    f32x2 d;
    asm("v_pk_mul_f32 %0, %1, %2" : "=v"(d) : "v"(a), "v"(b));
    return d;
}
__device__ __forceinline__ f32x2 pk_fma(f32x2 a, f32x2 b, f32x2 c) {
    f32x2 d;
    asm("v_pk_fma_f32 %0, %1, %2, %3" : "=v"(d) : "v"(a), "v"(b), "v"(c));
    return d;
}

// Exact distributed top-16 for query T (0/1): sorted list (ascending by
// (dist,idx)) in lanes 16T..16T+15; lane 16T+15 holds the exact threshold
// tau. d is the EXACT numpy distance. th = tau + qnm is the conservative
// dot-product-gate threshold (qnm = -|q|^2 + margin).
template <int T>
__device__ __forceinline__ void insert_all(float d, int p, int lane,
                                           float& ld, int& li, float& tau,
                                           float& th, float qnm)
{
    unsigned long long rem = __ballot(d <= tau);
    while (rem) {
        const int srcl = __ffsll(rem) - 1;           // wave-uniform
        const float wd = readlane_f(d, srcl);
        const int   wi = __builtin_amdgcn_readlane(p, srcl);
        const bool less = (ld < wd) || (ld == wd && li < wi);
        const unsigned long long lm = __ballot(less);
        const int pos = __popc((unsigned)((lm >> (16 * T)) & 0xffffull));
        const float pld = dpp_shr1_f(ld);
        const int   pli = dpp_shr1_i(li);
        if ((lane >> 4) == T) {
            const int gl = lane & 15;
            if (gl == pos)      { ld = wd;  li = wi;  }
            else if (gl > pos)  { ld = pld; li = pli; }
        }
        tau = readlane_f(ld, 16 * T + 15);
        th  = tau + qnm;                             // gate threshold update
        rem &= rem - 1;
        if (rem) rem &= __ballot(d <= tau);          // re-gate survivors (exact)
    }
}

// ---------------- pre-pass: AoS xyz -> SoA x[],y[],z[] ----------------
__global__ __launch_bounds__(256) void repack_soa(const float* __restrict__ xyz,
                                                  float* __restrict__ ws)
{
    const int i = blockIdx.x * 256 + threadIdx.x;    // 4-point group id
    const int b = i / (NPTS / 4);
    const int g = i % (NPTS / 4);
    const float4* src = (const float4*)(xyz + (size_t)b * NPTS * 3) + 3 * g;
    const float4 c0 = src[0], c1 = src[1], c2 = src[2];
    float* xs = ws + (size_t)b * 3 * NPTS;
    float* ys = xs + NPTS;
    float* zs = ys + NPTS;
    ((float4*)xs)[g] = make_float4(c0.x, c0.w, c1.z, c2.y);
    ((float4*)ys)[g] = make_float4(c0.y, c1.x, c1.w, c2.z);
    ((float4*)zs)[g] = make_float4(c0.z, c1.y, c2.x, c2.w);
}

// ---------------- main kernel (SoA, packed gate) ----------------
struct PtBuf { float4 x0, x1, y0, y1, z0, z1; };

__device__ __forceinline__ void loadbuf(PtBuf& b, const float* xs,
                                        const float* ys, const float* zs,
                                        unsigned o)
{
    b.x0 = *(const float4*)(xs + o);  b.x1 = *(const float4*)(xs + o + 4);
    b.y0 = *(const float4*)(ys + o);  b.y1 = *(const float4*)(ys + o + 4);
    b.z0 = *(const float4*)(zs + o);  b.z1 = *(const float4*)(zs + o + 4);
}

// One 512-point step: 8 pts/lane as 4 packed pairs; 13 VALU / 2 pts;
// exact recompute + exact insert for accepted slots.
__device__ __forceinline__ void step_soa(const PtBuf& c, int pb, int lane,
                                         f32x2 M2X0, f32x2 M2Y0, f32x2 M2Z0,
                                         f32x2 M2X1, f32x2 M2Y1, f32x2 M2Z1,
                                         float qx0, float qy0, float qz0,
                                         float qx1, float qy1, float qz1,
                                         float& ld, int& li,
                                         float& tau0, float& tau1,
                                         float& th0, float& th1,
                                         float qnm0, float qnm1)
{
    f32x2 X[4] = { {c.x0.x, c.x0.y}, {c.x0.z, c.x0.w},
                   {c.x1.x, c.x1.y}, {c.x1.z, c.x1.w} };
    f32x2 Y[4] = { {c.y0.x, c.y0.y}, {c.y0.z, c.y0.w},
                   {c.y1.x, c.y1.y}, {c.y1.z, c.y1.w} };
    f32x2 Z[4] = { {c.z0.x, c.z0.y}, {c.z0.z, c.z0.w},
                   {c.z1.x, c.z1.y}, {c.z1.z, c.z1.w} };

    unsigned long long m0[PPL], m1[PPL], any = 0;
    #pragma unroll
    for (int u = 0; u < 4; ++u) {                    // 2 points per trip
        const f32x2 s  = pk_fma(Z[u], Z[u], pk_fma(Y[u], Y[u], pk_mul(X[u], X[u])));
        const f32x2 t0 = pk_fma(Z[u], M2Z0, pk_fma(Y[u], M2Y0, pk_fma(X[u], M2X0, s)));
        const f32x2 t1 = pk_fma(Z[u], M2Z1, pk_fma(Y[u], M2Y1, pk_fma(X[u], M2X1, s)));
        m0[2*u]   = __ballot(t0.x <= th0);
        m0[2*u+1] = __ballot(t0.y <= th0);
        m1[2*u]   = __ballot(t1.x <= th1);
        m1[2*u+1] = __ballot(t1.y <= th1);
        any |= m0[2*u] | m0[2*u+1] | m1[2*u] | m1[2*u+1];
    }
    if (any) {
        #pragma unroll
        for (int j = 0; j < PPL; ++j) {
            if (m0[j]) {                             // exact numpy distance
                const float pxj = (j & 1) ? X[j >> 1].y : X[j >> 1].x;
                const float pyj = (j & 1) ? Y[j >> 1].y : Y[j >> 1].x;
                const float pzj = (j & 1) ? Z[j >> 1].y : Z[j >> 1].x;
                const float dx = __fadd_rn(pxj, -qx0);
                const float dy = __fadd_rn(pyj, -qy0);
                const float dz = __fadd_rn(pzj, -qz0);
                const float d  = __fadd_rn(
                    __fadd_rn(__fmul_rn(dx, dx), __fmul_rn(dy, dy)),
                    __fmul_rn(dz, dz));
                insert_all<0>(d, pb + j, lane, ld, li, tau0, th0, qnm0);
            }
        }
        #pragma unroll
        for (int j = 0; j < PPL; ++j) {
            if (m1[j]) {
                const float pxj = (j & 1) ? X[j >> 1].y : X[j >> 1].x;
                const float pyj = (j & 1) ? Y[j >> 1].y : Y[j >> 1].x;
                const float pzj = (j & 1) ? Z[j >> 1].y : Z[j >> 1].x;
                const float dx = __fadd_rn(pxj, -qx1);
                const float dy = __fadd_rn(pyj, -qy1);
                const float dz = __fadd_rn(pzj, -qz1);
                const float d  = __fadd_rn(
                    __fadd_rn(__fmul_rn(dx, dx), __fmul_rn(dy, dy)),
                    __fmul_rn(dz, dz));
                insert_all<1>(d, pb + j, lane, ld, li, tau1, th1, qnm1);
            }
        }
    }
}

// 1024 blocks x 4 waves = 4096 waves; natural VGPR (~80) — no min-waves
// bound (its cap semantics caused the R3/R4 spill disasters).
__global__ __launch_bounds__(BLOCK) void knn_soa(const float* __restrict__ ws,
                                                 float* __restrict__ out_idx,
                                                 float* __restrict__ out_pts)
{
    const int tid  = threadIdx.x;
    const int lane = tid & 63;
    const int wv   = tid >> 6;
    const int w    = blockIdx.x * WPB + wv;          // wave id in [0, 4096)
    const int b    = w >> 10;
    const int pr   = w & 1023;                       // query pair
    const float* xs = ws + (size_t)b * 3 * NPTS;
    const float* ys = xs + NPTS;
    const float* zs = ys + NPTS;

    const int qp0 = pr << 5;                         // stride-16 subsample
    const float qx0 = xs[qp0],      qy0 = ys[qp0],      qz0 = zs[qp0];
    const float qx1 = xs[qp0 + 16], qy1 = ys[qp0 + 16], qz1 = zs[qp0 + 16];

    const int g0 = b * NQ + (pr << 1);
    if (lane == 0) {
        out_pts[3 * g0 + 0] = qx0;
        out_pts[3 * g0 + 1] = qy0;
        out_pts[3 * g0 + 2] = qz0;
        out_pts[3 * g0 + 3] = qx1;
        out_pts[3 * g0 + 4] = qy1;
        out_pts[3 * g0 + 5] = qz1;
    }

    // Gate constants: packed {-2q,-2q}; qnm = -|q|^2 + margin.
    const f32x2 M2X0 = { -2.0f * qx0, -2.0f * qx0 };
    const f32x2 M2Y0 = { -2.0f * qy0, -2.0f * qy0 };
    const f32x2 M2Z0 = { -2.0f * qz0, -2.0f * qz0 };
    const f32x2 M2X1 = { -2.0f * qx1, -2.0f * qx1 };
    const f32x2 M2Y1 = { -2.0f * qy1, -2.0f * qy1 };
    const f32x2 M2Z1 = { -2.0f * qz1, -2.0f * qz1 };
    const float qnm0 = -(qx0 * qx0 + qy0 * qy0 + qz0 * qz0) + GATE_MARGIN;
    const float qnm1 = -(qx1 * qx1 + qy1 * qy1 + qz1 * qz1) + GATE_MARGIN;

    float ld = __builtin_inff();  int li = 0x7fffffff;
    float tau0 = __builtin_inff(), tau1 = __builtin_inff();
    float th0  = __builtin_inff(), th1  = __builtin_inff();

    // Lane's stream: 8 consecutive points per iteration; float-offset o.
    unsigned o = 8 * (unsigned)lane;

    PtBuf A, Bf;
    loadbuf(A, xs, ys, zs, o);                       // prologue (iter 0)
    int pb = PPL * lane;
    for (int k = 0; k < ITERS; k += 2) {             // double-buffered pipeline
        loadbuf(Bf, xs, ys, zs, o + 512);            // prefetch iter k+1
        step_soa(A, pb, lane, M2X0, M2Y0, M2Z0, M2X1, M2Y1, M2Z1,
                 qx0, qy0, qz0, qx1, qy1, qz1,
                 ld, li, tau0, tau1, th0, th1, qnm0, qnm1);
        if (k + 2 < ITERS)
            loadbuf(A, xs, ys, zs, o + 1024);        // prefetch iter k+2
        step_soa(Bf, pb + 512, lane, M2X0, M2Y0, M2Z0, M2X1, M2Y1, M2Z1,
                 qx0, qy0, qz0, qx1, qy1, qz1,
                 ld, li, tau0, tau1, th0, th1, qnm0, qnm1);
        o += 1024;
        pb += 1024;
    }

    // lanes 0..15: q0 ranks 0..15; lanes 16..31: q1 ranks (g1 = g0+1)
    if (lane < 2 * KNN) {
        out_idx[(size_t)g0 * KNN + lane] = (float)li;
    }
}

// ---------------- fallback: proven R9 kernel (AoS, scalar gate) ----------------
__device__ __forceinline__ void load6(float4 dst[6], const float4* p) {
    #pragma unroll
    for (int t = 0; t < 6; ++t) dst[t] = p[t];
}

__device__ __forceinline__ void step2(const float4 c[6], int pb, int lane,
                                      float m2x0, float m2y0, float m2z0,
                                      float m2x1, float m2y1, float m2z1,
                                      float qx0, float qy0, float qz0,
                                      float qx1, float qy1, float qz1,
                                      float& ld, int& li,
                                      float& tau0, float& tau1,
                                      float& th0, float& th1,
                                      float qnm0, float qnm1)
{
    float px[PPL], py[PPL], pz[PPL];
    px[0] = c[0].x; py[0] = c[0].y; pz[0] = c[0].z;
    px[1] = c[0].w; py[1] = c[1].x; pz[1] = c[1].y;
    px[2] = c[1].z; py[2] = c[1].w; pz[2] = c[2].x;
    px[3] = c[2].y; py[3] = c[2].z; pz[3] = c[2].w;
    px[4] = c[3].x; py[4] = c[3].y; pz[4] = c[3].z;
    px[5] = c[3].w; py[5] = c[4].x; pz[5] = c[4].y;
    px[6] = c[4].z; py[6] = c[4].w; pz[6] = c[5].x;
    px[7] = c[5].y; py[7] = c[5].z; pz[7] = c[5].w;

    unsigned long long m0[PPL], m1[PPL], any = 0;
    #pragma unroll
    for (int j = 0; j < PPL; ++j) {
        const float s = __fmaf_rn(pz[j], pz[j],
                          __fmaf_rn(py[j], py[j], __fmul_rn(px[j], px[j])));
        float t0 = __fmaf_rn(px[j], m2x0, s);
        t0 = __fmaf_rn(py[j], m2y0, t0);
        t0 = __fmaf_rn(pz[j], m2z0, t0);
        m0[j] = __ballot(t0 <= th0);
        float t1 = __fmaf_rn(px[j], m2x1, s);
        t1 = __fmaf_rn(py[j], m2y1, t1);
        t1 = __fmaf_rn(pz[j], m2z1, t1);
        m1[j] = __ballot(t1 <= th1);
        any |= m0[j] | m1[j];
    }
    if (any) {
        #pragma unroll
        for (int j = 0; j < PPL; ++j) {
            if (m0[j]) {
                const float dx = __fadd_rn(px[j], -qx0);
                const float dy = __fadd_rn(py[j], -qy0);
                const float dz = __fadd_rn(pz[j], -qz0);
                const float d  = __fadd_rn(
                    __fadd_rn(__fmul_rn(dx, dx), __fmul_rn(dy, dy)),
                    __fmul_rn(dz, dz));
                insert_all<0>(d, pb + j, lane, ld, li, tau0, th0, qnm0);
            }
        }
        #pragma unroll
        for (int j = 0; j < PPL; ++j) {
            if (m1[j]) {
                const float dx = __fadd_rn(px[j], -qx1);
                const float dy = __fadd_rn(py[j], -qy1);
                const float dz = __fadd_rn(pz[j], -qz1);
                const float d  = __fadd_rn(
                    __fadd_rn(__fmul_rn(dx, dx), __fmul_rn(dy, dy)),
                    __fmul_rn(dz, dz));
                insert_all<1>(d, pb + j, lane, ld, li, tau1, th1, qnm1);
            }
        }
    }
}

__global__ __launch_bounds__(BLOCK) void knn_aos(const float* __restrict__ xyz,
                                                 float* __restrict__ out_idx,
                                                 float* __restrict__ out_pts)
{
    const int tid  = threadIdx.x;
    const int lane = tid & 63;
    const int wv   = tid >> 6;
    const int w    = blockIdx.x * WPB + wv;
    const int b    = w >> 10;
    const int pr   = w & 1023;
    const size_t base = (size_t)b * NPTS * 3;

    const int qp0 = pr << 5;
    const float qx0 = xyz[base + 3 * qp0 + 0];
    const float qy0 = xyz[base + 3 * qp0 + 1];
    const float qz0 = xyz[base + 3 * qp0 + 2];
    const float qx1 = xyz[base + 3 * qp0 + 48];
    const float qy1 = xyz[base + 3 * qp0 + 49];
    const float qz1 = xyz[base + 3 * qp0 + 50];

    const int g0 = b * NQ + (pr << 1);
    if (lane == 0) {
        out_pts[3 * g0 + 0] = qx0;
        out_pts[3 * g0 + 1] = qy0;
        out_pts[3 * g0 + 2] = qz0;
        out_pts[3 * g0 + 3] = qx1;
        out_pts[3 * g0 + 4] = qy1;
        out_pts[3 * g0 + 5] = qz1;
    }

    const float m2x0 = -2.0f * qx0, m2y0 = -2.0f * qy0, m2z0 = -2.0f * qz0;
    const float m2x1 = -2.0f * qx1, m2y1 = -2.0f * qy1, m2z1 = -2.0f * qz1;
    const float qnm0 = -(qx0 * qx0 + qy0 * qy0 + qz0 * qz0) + GATE_MARGIN;
    const float qnm1 = -(qx1 * qx1 + qy1 * qy1 + qz1 * qz1) + GATE_MARGIN;

    float ld = __builtin_inff();  int li = 0x7fffffff;
    float tau0 = __builtin_inff(), tau1 = __builtin_inff();
    float th0  = __builtin_inff(), th1  = __builtin_inff();

    const float4* lp = (const float4*)(xyz + base) + 6 * lane;

    float4 A[6], Bf[6];
    load6(A, lp);
    for (int k = 0; k < ITERS; k += 2) {
        load6(Bf, lp + 384);
        step2(A, (k << 9) + PPL * lane, lane,
              m2x0, m2y0, m2z0, m2x1, m2y1, m2z1,
              qx0, qy0, qz0, qx1, qy1, qz1,
              ld, li, tau0, tau1, th0, th1, qnm0, qnm1);
        if (k + 2 < ITERS)
            load6(A, lp + 768);
        step2(Bf, ((k + 1) << 9) + PPL * lane, lane,
              m2x0, m2y0, m2z0, m2x1, m2y1, m2z1,
              qx0, qy0, qz0, qx1, qy1, qz1,
              ld, li, tau0, tau1, th0, th1, qnm0, qnm1);
        lp += 768;
    }

    if (lane < 2 * KNN) {
        out_idx[(size_t)g0 * KNN + lane] = (float)li;
    }
}

extern "C" void kernel_launch(void* const* d_in, const int* in_sizes, int n_in,
                              void* d_out, int out_size, void* d_ws, size_t ws_size,
                              hipStream_t stream) {
    const float* xyz = (const float*)d_in[0];
    float* out = (float*)d_out;
    float* out_idx = out;                                 // NB*NQ*KNN floats
    float* out_pts = out + (size_t)NB * NQ * KNN;         // NB*NQ*3 floats

    const size_t ws_needed = (size_t)NB * 3 * NPTS * sizeof(float);  // 1.57 MB
    const int blocks = (NB * NQ / 2) / WPB;               // 1024
    if (d_ws != nullptr && ws_size >= ws_needed) {
        float* wsp = (float*)d_ws;
        repack_soa<<<NB * NPTS / 4 / 256, 256, 0, stream>>>(xyz, wsp);
        knn_soa<<<blocks, BLOCK, 0, stream>>>(wsp, out_idx, out_pts);
    } else {
        knn_aos<<<blocks, BLOCK, 0, stream>>>(xyz, out_idx, out_pts);
    }
}